// Round 9
// baseline (449.018 us; speedup 1.0000x reference)
//
#include <hip/hip_runtime.h>
#include <hip/hip_bf16.h>

#define B_   8
#define S_   1024
#define HID_ 1024
#define H_   16
#define D_   64

typedef __hip_bfloat16 bf16;
typedef __attribute__((ext_vector_type(8))) short s16x8;   // MFMA A/B frag (8 bf16)
typedef __attribute__((ext_vector_type(4))) float f32x4;   // MFMA C/D frag

// f32 -> bf16 bits, round-half-up (add + shift; 2 VALU)
__device__ __forceinline__ short f2b(float f) {
    union { float f; unsigned u; } a; a.f = f;
    return (short)((a.u + 0x8000u) >> 16);
}
// load 8 consecutive f32 (32B, aligned) -> bf16 half-fragment
__device__ __forceinline__ s16x8 cvt8(const float* p) {
    const float4* q = (const float4*)p;
    float4 u = q[0], v = q[1];
    s16x8 r;
    r[0] = f2b(u.x); r[1] = f2b(u.y); r[2] = f2b(u.z); r[3] = f2b(u.w);
    r[4] = f2b(v.x); r[5] = f2b(v.y); r[6] = f2b(v.z); r[7] = f2b(v.w);
    return r;
}
__device__ __forceinline__ s16x8 load8bf(const bf16* p) {
    return *(const s16x8*)p;   // 16B load; callers guarantee alignment
}

// ---------------------------------------------------------------------------
// Kernel 0: one-shot W f32 -> bf16.
// ---------------------------------------------------------------------------
__global__ __launch_bounds__(256) void cvt_w(
    const float* __restrict__ Wq, const float* __restrict__ Wk,
    const float* __restrict__ Wv, bf16* __restrict__ Wb)
{
    const float* srcs[3] = {Wq, Wk, Wv};
    const float* src = srcs[blockIdx.y];
    bf16* dst = Wb + (size_t)blockIdx.y * (H_ * D_ * D_);
    const int i = (blockIdx.x * 256 + threadIdx.x) * 8;
    *(s16x8*)(dst + i) = cvt8(src + i);
}

// ---------------------------------------------------------------------------
// Kernel 1: QKV projection. 1D grid 1024 with the SAME XCD swizzle as attn
// (bh = id&127) so the Q/K/VT tiles a block writes stay in the L2 of the
// XCD whose attn blocks will read them. x tile staged through LDS
// (coalesced float4). Q,K: [B,H,S,D]; V transposed VT: [B,H,D,S].
// ---------------------------------------------------------------------------
__global__ __launch_bounds__(256) void qkv_proj(
    const float* __restrict__ x, const bf16* __restrict__ Wb,
    const float* __restrict__ bq, const float* __restrict__ bk,
    const float* __restrict__ bv,
    bf16* __restrict__ Q, bf16* __restrict__ K, bf16* __restrict__ VT)
{
    __shared__ __align__(16) bf16 xs[128][72];   // 18 KiB, stride-72 padding

    const int id = blockIdx.x;
    const int bh_i = id & 127, sc = id >> 7;
    const int b = bh_i >> 4, h = bh_i & 15;
    const int t = threadIdx.x;
    const int wave = t >> 6, lane = t & 63;
    const int quad = lane >> 4, c = lane & 15;
    const int s0 = sc * 128 + wave * 32;
    const size_t bh = (size_t)b * H_ + h;

    // ---- stage x[rows sc*128..+128)[h*64..+64) -> bf16 LDS, coalesced ----
    {
        const float* xg = x + ((size_t)b * S_ + sc * 128) * HID_ + h * D_;
#pragma unroll
        for (int i = 0; i < 8; ++i) {
            const int j = i * 256 + t;          // 2048 float4 segments
            const int row = j >> 4, seg = j & 15;
            float4 v = *(const float4*)(xg + (size_t)row * HID_ + seg * 4);
            short4 pk;
            pk.x = f2b(v.x); pk.y = f2b(v.y); pk.z = f2b(v.z); pk.w = f2b(v.w);
            *(short4*)&xs[row][seg * 4] = pk;
        }
    }
    __syncthreads();

    s16x8 xa[2][2];
#pragma unroll
    for (int mt = 0; mt < 2; ++mt) {
        xa[mt][0] = *(const s16x8*)&xs[wave * 32 + mt * 16 + c][quad * 8];
        xa[mt][1] = *(const s16x8*)&xs[wave * 32 + mt * 16 + c][32 + quad * 8];
    }

    const float* bs[3] = {bq, bk, bv};

#pragma unroll
    for (int m = 0; m < 3; ++m) {
        const bf16*  W    = Wb + ((size_t)m * H_ + h) * (D_ * D_);
        const float* bias = bs[m] + h * D_;
#pragma unroll
        for (int et = 0; et < 4; ++et) {
            const bf16* wrow = W + (et * 16 + c) * D_ + quad * 8;
            s16x8 wf0 = load8bf(wrow);
            s16x8 wf1 = load8bf(wrow + 32);
            if (m < 2) {
                // D[e][s] = W·X^T : col = s (lane c), row = e (quad*4+r)
                const float4 bb = *(const float4*)&bias[et * 16 + quad * 4];
#pragma unroll
                for (int mt = 0; mt < 2; ++mt) {
                    f32x4 acc = {0.f, 0.f, 0.f, 0.f};
                    acc = __builtin_amdgcn_mfma_f32_16x16x32_bf16(wf0, xa[mt][0], acc, 0, 0, 0);
                    acc = __builtin_amdgcn_mfma_f32_16x16x32_bf16(wf1, xa[mt][1], acc, 0, 0, 0);
                    bf16* dst = (m == 0 ? Q : K) +
                        (bh * S_ + s0 + mt * 16 + c) * D_ + et * 16 + quad * 4;
                    short4 pk;
                    pk.x = f2b(acc[0] + bb.x);
                    pk.y = f2b(acc[1] + bb.y);
                    pk.z = f2b(acc[2] + bb.z);
                    pk.w = f2b(acc[3] + bb.w);
                    *(short4*)dst = pk;
                }
            } else {
                // D[s][e] = X·W^T : col = e (lane c), row = s (quad*4+r)
                const float bbv = bias[et * 16 + c];
#pragma unroll
                for (int mt = 0; mt < 2; ++mt) {
                    f32x4 acc = {0.f, 0.f, 0.f, 0.f};
                    acc = __builtin_amdgcn_mfma_f32_16x16x32_bf16(xa[mt][0], wf0, acc, 0, 0, 0);
                    acc = __builtin_amdgcn_mfma_f32_16x16x32_bf16(xa[mt][1], wf1, acc, 0, 0, 0);
                    bf16* dst = VT + (bh * D_ + et * 16 + c) * S_ + s0 + mt * 16 + quad * 4;
                    short4 pk;
                    pk.x = f2b(acc[0] + bbv);
                    pk.y = f2b(acc[1] + bbv);
                    pk.z = f2b(acc[2] + bbv);
                    pk.w = f2b(acc[3] + bbv);
                    *(short4*)dst = pk;
                }
            }
        }
    }
}

// ---------------------------------------------------------------------------
// Kernel 2: MFMA flash attention, register-resident P (operand-swap trick).
// S^T = K·Q^T puts each lane's scores at (query = lane&15, keys = quad*4+r),
// which IS the A-operand slot layout for P·V when each 16x16x32 PV MFMA
// packs two 16-key chunks. No LDS / barriers / cross-lane in the K-loop.
// grid 2048 (XCD swizzle bh = id&127; qc = id>>7 over 16 chunks of 64 rows;
// wave owns 16 query rows) -> 8 blocks/CU available for latency hiding.
// ---------------------------------------------------------------------------
__global__ __launch_bounds__(256, 5) void attn(
    const bf16* __restrict__ Q, const bf16* __restrict__ K,
    const bf16* __restrict__ VT, float* __restrict__ out)
{
    __shared__ __align__(16) float os[4][16][68];   // wave-private store staging

    const int id = blockIdx.x;
    const int bh_i = id & 127, qc = id >> 7;
    const int b = bh_i >> 4, h = bh_i & 15;
    const int wave = threadIdx.x >> 6, lane = threadIdx.x & 63;
    const int quad = lane >> 4, c = lane & 15;
    const int q0 = qc * 64 + wave * 16;
    const size_t bh = (size_t)b * H_ + h;

    // Q fragments (B-operand of the swapped QK), register-resident
    s16x8 aq0, aq1;
    {
        const bf16* qrow = Q + (bh * S_ + q0 + c) * D_ + quad * 8;
        aq0 = load8bf(qrow);
        aq1 = load8bf(qrow + 32);
    }

    f32x4 o[4];
#pragma unroll
    for (int et = 0; et < 4; ++et) o[et] = {0.f, 0.f, 0.f, 0.f};
    float l = 0.f;   // per-lane partial denom (query c, this quad's keys)

    const float CEXP = 0.18033688011112042f;           // (1/sqrt(64))*log2(e)
    const float NM0  = -16.0f * 0.18033688011112042f;  // fixed shift m0=16

    const bf16* Kbase = K  + bh * (size_t)(S_ * D_) + c * D_ + quad * 8;
    const bf16* Vbase = VT + bh * (size_t)(D_ * S_);

    s16x8 ka[4], kb[4];
#pragma unroll
    for (int ct = 0; ct < 4; ++ct) {
        ka[ct] = load8bf(Kbase + ct * 16 * D_);
        kb[ct] = load8bf(Kbase + ct * 16 * D_ + 32);
    }

#pragma unroll 2
    for (int kt = 0; kt < S_ / 64; ++kt) {
        // ---- V fragments for this tile (paired-chunk B layout; 8B reads) --
        s16x8 vf[4][2];
        const bf16* Vt0 = Vbase + kt * 64;
#pragma unroll
        for (int et = 0; et < 4; ++et)
#pragma unroll
            for (int p = 0; p < 2; ++p) {
                const bf16* vr = Vt0 + (et * 16 + c) * S_ + p * 32 + quad * 4;
                short4 lo = *(const short4*)vr;          // chunk 2p keys
                short4 hi = *(const short4*)(vr + 16);   // chunk 2p+1 keys
                s16x8 v;
                v[0] = lo.x; v[1] = lo.y; v[2] = lo.z; v[3] = lo.w;
                v[4] = hi.x; v[5] = hi.y; v[6] = hi.z; v[7] = hi.w;
                vf[et][p] = v;
            }

        // ---- S^T = K·Q^T : lane holds S[query c][key ct*16+quad*4+r] ----
        f32x4 s[4];
#pragma unroll
        for (int ct = 0; ct < 4; ++ct) {
            f32x4 acc = {0.f, 0.f, 0.f, 0.f};
            acc = __builtin_amdgcn_mfma_f32_16x16x32_bf16(ka[ct], aq0, acc, 0, 0, 0);
            acc = __builtin_amdgcn_mfma_f32_16x16x32_bf16(kb[ct], aq1, acc, 0, 0, 0);
            s[ct] = acc;
        }

        // ---- prefetch K(kt+1) (covered by softmax+PV) ----
        {
            const bf16* Kn = Kbase + (size_t)(((kt + 1) & 15) * 64) * D_;
#pragma unroll
            for (int ct = 0; ct < 4; ++ct) {
                ka[ct] = load8bf(Kn + ct * 16 * D_);
                kb[ct] = load8bf(Kn + ct * 16 * D_ + 32);
            }
        }

        // ---- fixed-shift softmax numerators, packed straight into A-frags --
        s16x8 pz[2];
#pragma unroll
        for (int p = 0; p < 2; ++p) {
            s16x8 z;
#pragma unroll
            for (int j = 0; j < 4; ++j) {
                float pa = __builtin_amdgcn_exp2f(fmaf(s[2 * p][j],     CEXP, NM0));
                float pb = __builtin_amdgcn_exp2f(fmaf(s[2 * p + 1][j], CEXP, NM0));
                l += pa + pb;
                z[j]     = f2b(pa);
                z[4 + j] = f2b(pb);
            }
            pz[p] = z;
        }

        // ---- O += P·V, P never left registers ----
#pragma unroll
        for (int et = 0; et < 4; ++et) {
            o[et] = __builtin_amdgcn_mfma_f32_16x16x32_bf16(pz[0], vf[et][0], o[et], 0, 0, 0);
            o[et] = __builtin_amdgcn_mfma_f32_16x16x32_bf16(pz[1], vf[et][1], o[et], 0, 0, 0);
        }
    }

    // ---- epilogue ----
    // full denom for query c: sum partials across the 4 quads
    float L = l;
    L += __shfl_xor(L, 16, 64);
    L += __shfl_xor(L, 32, 64);
    const float Linv = 1.0f / L;
    float inv[4];
#pragma unroll
    for (int r = 0; r < 4; ++r)
        inv[r] = __shfl(Linv, quad * 4 + r, 64);   // inv for o-row quad*4+r

    // normalize + transpose through wave-private LDS -> contiguous float4 rows
#pragma unroll
    for (int et = 0; et < 4; ++et)
#pragma unroll
        for (int r = 0; r < 4; ++r)
            os[wave][quad * 4 + r][et * 16 + c] = o[et][r] * inv[r];
    float* orow = out + ((size_t)b * S_ + q0 + c) * HID_ + h * D_;
#pragma unroll
    for (int j = 0; j < 4; ++j) {
        float4 v = *(const float4*)&os[wave][c][(quad + j * 4) * 4];
        *(float4*)(orow + (quad + j * 4) * 4) = v;
    }
}

// ---------------------------------------------------------------------------
extern "C" void kernel_launch(void* const* d_in, const int* in_sizes, int n_in,
                              void* d_out, int out_size, void* d_ws, size_t ws_size,
                              hipStream_t stream) {
    (void)in_sizes; (void)n_in; (void)out_size; (void)ws_size;
    const float* x  = (const float*)d_in[0];
    const float* Wq = (const float*)d_in[1];
    const float* bq = (const float*)d_in[2];
    const float* Wk = (const float*)d_in[3];
    const float* bk = (const float*)d_in[4];
    const float* Wv = (const float*)d_in[5];
    const float* bv = (const float*)d_in[6];
    float* outp = (float*)d_out;   // reference output dtype is float32

    const size_t nelem = (size_t)B_ * H_ * S_ * D_;   // 8M elems
    bf16* Qw  = (bf16*)d_ws;
    bf16* Kw  = Qw + nelem;
    bf16* VTw = Kw + nelem;
    bf16* Wbw = VTw + nelem;       // 3*H*D*D bf16 = 384 KiB extra

    cvt_w<<<dim3(32, 3), 256, 0, stream>>>(Wq, Wk, Wv, Wbw);
    qkv_proj<<<dim3(1024), 256, 0, stream>>>(x, Wbw, bq, bk, bv, Qw, Kw, VTw);
    attn<<<dim3(2048), 256, 0, stream>>>(Qw, Kw, VTw, outp);
}

// Round 10
// 181.859 us; speedup vs baseline: 2.4690x; 2.4690x over previous
//
#include <hip/hip_runtime.h>
#include <hip/hip_bf16.h>

#define B_   8
#define S_   1024
#define HID_ 1024
#define H_   16
#define D_   64

typedef __hip_bfloat16 bf16;
typedef __attribute__((ext_vector_type(8))) short s16x8;   // MFMA A/B frag (8 bf16)
typedef __attribute__((ext_vector_type(4))) float f32x4;   // MFMA C/D frag

// Fragment-order workspace layouts (all indices in bf16 elements):
//  Qf/Kf: per bh (128 KiB): 64 row-tiles of 16 rows; per tile 1024 elems =
//         [half(2)][lane(64)][8]; lane (quad,c) slot holds row c, features
//         half*32 + quad*8 .. +8.   (= exactly the A/B frag attn needs)
//  Vf:    per bh: 16 key-tiles; per tile 4096 = [et(4)][p(2)][lane(64)][8];
//         lane slot = V[key p*32+quad*4+j][feat et*16+c] (j=0..3) and
//         key+16 (j=4..7) — the paired-chunk PV B-frag.
#define QK_BH 65536   // elems per bh in Qf/Kf
#define V_BH  65536   // elems per bh in Vf

// f32 -> bf16 bits, round-half-up (add + shift; 2 VALU)
__device__ __forceinline__ short f2b(float f) {
    union { float f; unsigned u; } a; a.f = f;
    return (short)((a.u + 0x8000u) >> 16);
}
// load 8 consecutive f32 (32B, aligned) -> bf16 half-fragment
__device__ __forceinline__ s16x8 cvt8(const float* p) {
    const float4* q = (const float4*)p;
    float4 u = q[0], v = q[1];
    s16x8 r;
    r[0] = f2b(u.x); r[1] = f2b(u.y); r[2] = f2b(u.z); r[3] = f2b(u.w);
    r[4] = f2b(v.x); r[5] = f2b(v.y); r[6] = f2b(v.z); r[7] = f2b(v.w);
    return r;
}
__device__ __forceinline__ s16x8 load8bf(const bf16* p) {
    return *(const s16x8*)p;   // 16B load; callers guarantee alignment
}

// ---------------------------------------------------------------------------
// Kernel 0: one-shot W f32 -> bf16.
// ---------------------------------------------------------------------------
__global__ __launch_bounds__(256) void cvt_w(
    const float* __restrict__ Wq, const float* __restrict__ Wk,
    const float* __restrict__ Wv, bf16* __restrict__ Wb)
{
    const float* srcs[3] = {Wq, Wk, Wv};
    const float* src = srcs[blockIdx.y];
    bf16* dst = Wb + (size_t)blockIdx.y * (H_ * D_ * D_);
    const int i = (blockIdx.x * 256 + threadIdx.x) * 8;
    *(s16x8*)(dst + i) = cvt8(src + i);
}

// ---------------------------------------------------------------------------
// Kernel 1: QKV projection writing FRAGMENT-ORDER workspace.
// 1D grid 1024, XCD swizzle (bh = id&127) matching attn. x tile staged
// through LDS (coalesced float4). All output stores are 8B, contiguous
// across the wave for each (m,et,mt) step.
// ---------------------------------------------------------------------------
__global__ __launch_bounds__(256) void qkv_proj(
    const float* __restrict__ x, const bf16* __restrict__ Wb,
    const float* __restrict__ bq, const float* __restrict__ bk,
    const float* __restrict__ bv,
    bf16* __restrict__ Qf, bf16* __restrict__ Kf, bf16* __restrict__ Vf)
{
    __shared__ __align__(16) bf16 xs[128][72];   // 18 KiB, stride-72 padding

    const int id = blockIdx.x;
    const int bh_i = id & 127, sc = id >> 7;
    const int b = bh_i >> 4, h = bh_i & 15;
    const int t = threadIdx.x;
    const int wave = t >> 6, lane = t & 63;
    const int quad = lane >> 4, c = lane & 15;
    const size_t bh = (size_t)bh_i;

    // ---- stage x[rows sc*128..+128)[h*64..+64) -> bf16 LDS, coalesced ----
    {
        const float* xg = x + ((size_t)b * S_ + sc * 128) * HID_ + h * D_;
#pragma unroll
        for (int i = 0; i < 8; ++i) {
            const int j = i * 256 + t;          // 2048 float4 segments
            const int row = j >> 4, seg = j & 15;
            float4 v = *(const float4*)(xg + (size_t)row * HID_ + seg * 4);
            short4 pk;
            pk.x = f2b(v.x); pk.y = f2b(v.y); pk.z = f2b(v.z); pk.w = f2b(v.w);
            *(short4*)&xs[row][seg * 4] = pk;
        }
    }
    __syncthreads();

    // X frags for this wave's 2 row-tiles (rows wave*32 + mt*16 + c)
    s16x8 xa[2][2];
#pragma unroll
    for (int mt = 0; mt < 2; ++mt) {
        xa[mt][0] = *(const s16x8*)&xs[wave * 32 + mt * 16 + c][quad * 8];
        xa[mt][1] = *(const s16x8*)&xs[wave * 32 + mt * 16 + c][32 + quad * 8];
    }

    const float* bs[3] = {bq, bk, bv};

#pragma unroll
    for (int m = 0; m < 3; ++m) {
        const bf16*  W    = Wb + ((size_t)m * H_ + h) * (D_ * D_);
        const float* bias = bs[m] + h * D_;
#pragma unroll
        for (int et = 0; et < 4; ++et) {
            const bf16* wrow = W + (et * 16 + c) * D_ + quad * 8;
            s16x8 wf0 = load8bf(wrow);
            s16x8 wf1 = load8bf(wrow + 32);
            if (m < 2) {
                // D[e][s] = W·X^T : lane holds features f = et*16+quad*4+r of
                // row s = (tile)*16 + c. Fragment target: half hp = f>>5,
                // octet qp = (f>>3)&3, byte j = (quad&1)*4+r.
                const int hp = et >> 1;
                const int qp = (2 * et + (quad >> 1)) & 3;
                const float4 bb = *(const float4*)&bias[et * 16 + quad * 4];
                bf16* base = (m == 0 ? Qf : Kf) + bh * QK_BH;
#pragma unroll
                for (int mt = 0; mt < 2; ++mt) {
                    f32x4 acc = {0.f, 0.f, 0.f, 0.f};
                    acc = __builtin_amdgcn_mfma_f32_16x16x32_bf16(wf0, xa[mt][0], acc, 0, 0, 0);
                    acc = __builtin_amdgcn_mfma_f32_16x16x32_bf16(wf1, xa[mt][1], acc, 0, 0, 0);
                    const int ts = sc * 8 + wave * 2 + mt;   // row-tile index
                    bf16* dst = base + ts * 1024 + hp * 512 +
                                (qp * 16 + c) * 8 + (quad & 1) * 4;
                    short4 pk;
                    pk.x = f2b(acc[0] + bb.x);
                    pk.y = f2b(acc[1] + bb.y);
                    pk.z = f2b(acc[2] + bb.z);
                    pk.w = f2b(acc[3] + bb.w);
                    *(short4*)dst = pk;
                }
            } else {
                // D[s][e] = X·W^T : lane holds keys k = (tile)+quad*4+r of
                // feature e = et*16+c. Fragment target: kt = sc*2+(wave>>1),
                // p = wave&1, half j-group = mt, quad' = quad, c' = c.
                const float bbv = bias[et * 16 + c];
                const int kt = sc * 2 + (wave >> 1);
                const int p  = wave & 1;
                bf16* base = Vf + bh * V_BH + kt * 4096 + et * 1024 + p * 512;
#pragma unroll
                for (int mt = 0; mt < 2; ++mt) {
                    f32x4 acc = {0.f, 0.f, 0.f, 0.f};
                    acc = __builtin_amdgcn_mfma_f32_16x16x32_bf16(xa[mt][0], wf0, acc, 0, 0, 0);
                    acc = __builtin_amdgcn_mfma_f32_16x16x32_bf16(xa[mt][1], wf1, acc, 0, 0, 0);
                    bf16* dst = base + (quad * 16 + c) * 8 + mt * 4;
                    short4 pk;
                    pk.x = f2b(acc[0] + bbv);
                    pk.y = f2b(acc[1] + bbv);
                    pk.z = f2b(acc[2] + bbv);
                    pk.w = f2b(acc[3] + bbv);
                    *(short4*)dst = pk;
                }
            }
        }
    }
}

// ---------------------------------------------------------------------------
// Kernel 2: MFMA flash attention, register-resident P, FRAGMENT-ORDER loads:
// every global load in the K-loop is `base + lane*16B` (fully coalesced,
// ~8 lines/instr) — removes the TA address-divergence serialization that
// capped rounds 6-9. grid 2048 (XCD swizzle bh = id&127), block 256,
// 16 q-rows/wave. No LDS/barriers/cross-lane in the loop.
// ---------------------------------------------------------------------------
__global__ __launch_bounds__(256, 3) void attn(
    const bf16* __restrict__ Qf, const bf16* __restrict__ Kf,
    const bf16* __restrict__ Vf, float* __restrict__ out)
{
    __shared__ __align__(16) float os[4][16][68];   // wave-private store staging

    const int id = blockIdx.x;
    const int bh_i = id & 127, qc = id >> 7;
    const int b = bh_i >> 4, h = bh_i & 15;
    const int wave = threadIdx.x >> 6, lane = threadIdx.x & 63;
    const int quad = lane >> 4, c = lane & 15;
    const int q0 = qc * 64 + wave * 16;
    const size_t bh = (size_t)bh_i;

    // Q fragments (B-operand of swapped QK), register-resident
    const bf16* Qb = Qf + bh * QK_BH + (qc * 4 + wave) * 1024 + lane * 8;
    const s16x8 aq0 = load8bf(Qb);
    const s16x8 aq1 = load8bf(Qb + 512);

    f32x4 o[4];
#pragma unroll
    for (int et = 0; et < 4; ++et) o[et] = {0.f, 0.f, 0.f, 0.f};
    float l = 0.f;   // per-lane partial denom (query c, this quad's keys)

    const float CEXP = 0.18033688011112042f;           // (1/sqrt(64))*log2(e)
    const float NM0  = -16.0f * 0.18033688011112042f;  // fixed shift m0=16

    const bf16* Kb = Kf + bh * QK_BH + lane * 8;
    const bf16* Vb = Vf + bh * V_BH  + lane * 8;

#pragma unroll 1
    for (int kt = 0; kt < S_ / 64; ++kt) {
        // ---- all tile loads up front: 16 independent coalesced 16B loads --
        s16x8 vf4[4][2];
#pragma unroll
        for (int et = 0; et < 4; ++et)
#pragma unroll
            for (int p = 0; p < 2; ++p)
                vf4[et][p] = load8bf(Vb + kt * 4096 + et * 1024 + p * 512);
        s16x8 ka[4], kb2[4];
#pragma unroll
        for (int ct = 0; ct < 4; ++ct) {
            ka[ct]  = load8bf(Kb + (kt * 4 + ct) * 1024);
            kb2[ct] = load8bf(Kb + (kt * 4 + ct) * 1024 + 512);
        }

        // ---- S^T = K·Q^T : lane holds S[query c][key ct*16+quad*4+r] ----
        f32x4 s[4];
#pragma unroll
        for (int ct = 0; ct < 4; ++ct) {
            f32x4 acc = {0.f, 0.f, 0.f, 0.f};
            acc = __builtin_amdgcn_mfma_f32_16x16x32_bf16(ka[ct],  aq0, acc, 0, 0, 0);
            acc = __builtin_amdgcn_mfma_f32_16x16x32_bf16(kb2[ct], aq1, acc, 0, 0, 0);
            s[ct] = acc;
        }

        // ---- fixed-shift softmax numerators, packed straight into A-frags --
        s16x8 pz[2];
#pragma unroll
        for (int p = 0; p < 2; ++p) {
            s16x8 z;
#pragma unroll
            for (int j = 0; j < 4; ++j) {
                float pa = __builtin_amdgcn_exp2f(fmaf(s[2 * p][j],     CEXP, NM0));
                float pb = __builtin_amdgcn_exp2f(fmaf(s[2 * p + 1][j], CEXP, NM0));
                l += pa + pb;
                z[j]     = f2b(pa);
                z[4 + j] = f2b(pb);
            }
            pz[p] = z;
        }

        // ---- O += P·V, P never leaves registers ----
#pragma unroll
        for (int et = 0; et < 4; ++et) {
            o[et] = __builtin_amdgcn_mfma_f32_16x16x32_bf16(pz[0], vf4[et][0], o[et], 0, 0, 0);
            o[et] = __builtin_amdgcn_mfma_f32_16x16x32_bf16(pz[1], vf4[et][1], o[et], 0, 0, 0);
        }
    }

    // ---- epilogue: quad-sum denom, normalize, LDS transpose, float4 out ----
    float L = l;
    L += __shfl_xor(L, 16, 64);
    L += __shfl_xor(L, 32, 64);
    const float Linv = 1.0f / L;
    float inv[4];
#pragma unroll
    for (int r = 0; r < 4; ++r)
        inv[r] = __shfl(Linv, quad * 4 + r, 64);   // denom for o-row quad*4+r

#pragma unroll
    for (int et = 0; et < 4; ++et)
#pragma unroll
        for (int r = 0; r < 4; ++r)
            os[wave][quad * 4 + r][et * 16 + c] = o[et][r] * inv[r];
    float* orow = out + ((size_t)b * S_ + q0 + c) * HID_ + h * D_;
#pragma unroll
    for (int j = 0; j < 4; ++j) {
        float4 v = *(const float4*)&os[wave][c][(quad + j * 4) * 4];
        *(float4*)(orow + (quad + j * 4) * 4) = v;
    }
}

// ---------------------------------------------------------------------------
extern "C" void kernel_launch(void* const* d_in, const int* in_sizes, int n_in,
                              void* d_out, int out_size, void* d_ws, size_t ws_size,
                              hipStream_t stream) {
    (void)in_sizes; (void)n_in; (void)out_size; (void)ws_size;
    const float* x  = (const float*)d_in[0];
    const float* Wq = (const float*)d_in[1];
    const float* bq = (const float*)d_in[2];
    const float* Wk = (const float*)d_in[3];
    const float* bk = (const float*)d_in[4];
    const float* Wv = (const float*)d_in[5];
    const float* bv = (const float*)d_in[6];
    float* outp = (float*)d_out;   // reference output dtype is float32

    bf16* Qfw = (bf16*)d_ws;                       // 128 bh * 64K elems
    bf16* Kfw = Qfw + (size_t)128 * QK_BH;
    bf16* Vfw = Kfw + (size_t)128 * QK_BH;
    bf16* Wbw = Vfw + (size_t)128 * V_BH;          // + 384 KiB for bf16 W

    cvt_w<<<dim3(32, 3), 256, 0, stream>>>(Wq, Wk, Wv, Wbw);
    qkv_proj<<<dim3(1024), 256, 0, stream>>>(x, Wbw, bq, bk, bv, Qfw, Kfw, Vfw);
    attn<<<dim3(2048), 256, 0, stream>>>(Qfw, Kfw, Vfw, outp);
}

// Round 11
// 163.662 us; speedup vs baseline: 2.7436x; 1.1112x over previous
//
#include <hip/hip_runtime.h>
#include <hip/hip_bf16.h>

#define B_   8
#define S_   1024
#define HID_ 1024
#define H_   16
#define D_   64

typedef __hip_bfloat16 bf16;
typedef __attribute__((ext_vector_type(8))) short s16x8;   // MFMA A/B frag (8 bf16)
typedef __attribute__((ext_vector_type(4))) float f32x4;   // MFMA C/D frag

// Fragment-order workspace layouts (indices in bf16 elements):
//  Qf/Kf: per bh (128 KiB): 64 row-tiles of 16 rows; per tile 1024 elems =
//         [half(2)][lane(64)][8]; lane (quad,c) holds row c, features
//         half*32+quad*8..+8  (exactly the attn A/B frag).
//  Vf:    per bh: 16 key-tiles; per tile 4096 = [et(4)][p(2)][lane(64)][8];
//         lane slot = V[key p*32+quad*4+j][feat et*16+c] (j=0..3), key+16
//         for j=4..7 — the paired-chunk PV B-frag.
//  Wf:    per (m,h): 4096 = [et(4)][half(2)][lane(64)][8]; lane slot =
//         W[e=et*16+c][d=half*32+quad*8+j] — qkv's W frag, coalesced.
#define QK_BH 65536
#define V_BH  65536

// f32 -> bf16 bits, round-half-up (add + shift; 2 VALU)
__device__ __forceinline__ short f2b(float f) {
    union { float f; unsigned u; } a; a.f = f;
    return (short)((a.u + 0x8000u) >> 16);
}
// load 8 consecutive f32 (32B, aligned) -> bf16 half-fragment
__device__ __forceinline__ s16x8 cvt8(const float* p) {
    const float4* q = (const float4*)p;
    float4 u = q[0], v = q[1];
    s16x8 r;
    r[0] = f2b(u.x); r[1] = f2b(u.y); r[2] = f2b(u.z); r[3] = f2b(u.w);
    r[4] = f2b(v.x); r[5] = f2b(v.y); r[6] = f2b(v.z); r[7] = f2b(v.w);
    return r;
}
__device__ __forceinline__ s16x8 load8bf(const bf16* p) {
    return *(const s16x8*)p;   // 16B load; callers guarantee alignment
}

// ---------------------------------------------------------------------------
// Kernel 0: one-shot W f32 -> bf16 in FRAGMENT ORDER.
// grid (32,3) x 256; thread -> one 8-elem fragment slot.
// ---------------------------------------------------------------------------
__global__ __launch_bounds__(256) void cvt_w(
    const float* __restrict__ Wq, const float* __restrict__ Wk,
    const float* __restrict__ Wv, bf16* __restrict__ Wf)
{
    const float* srcs[3] = {Wq, Wk, Wv};
    const float* src = srcs[blockIdx.y];
    bf16* dst = Wf + (size_t)blockIdx.y * (H_ * D_ * D_);
    const int i = blockIdx.x * 256 + threadIdx.x;   // 0..8191
    const int h = i >> 9;            // 512 threads per head
    const int r = i & 511;
    const int et = r >> 7, half = (r >> 6) & 1, lane = r & 63;
    const int quad = lane >> 4, c = lane & 15;
    const float* s = src + h * 4096 + (et * 16 + c) * 64 + half * 32 + quad * 8;
    bf16* d = dst + h * 4096 + et * 1024 + half * 512 + lane * 8;
    *(s16x8*)d = cvt8(s);
}

// ---------------------------------------------------------------------------
// Kernel 1: QKV projection writing FRAGMENT-ORDER workspace; W reads are
// now also fragment-order (base + lane*8, coalesced, L2-hot).
// 1D grid 1024, XCD swizzle (bh = id&127). x staged via LDS (coalesced).
// ---------------------------------------------------------------------------
__global__ __launch_bounds__(256) void qkv_proj(
    const float* __restrict__ x, const bf16* __restrict__ Wf,
    const float* __restrict__ bq, const float* __restrict__ bk,
    const float* __restrict__ bv,
    bf16* __restrict__ Qf, bf16* __restrict__ Kf, bf16* __restrict__ Vf)
{
    __shared__ __align__(16) bf16 xs[128][72];   // 18 KiB, stride-72 padding

    const int id = blockIdx.x;
    const int bh_i = id & 127, sc = id >> 7;
    const int b = bh_i >> 4, h = bh_i & 15;
    const int t = threadIdx.x;
    const int wave = t >> 6, lane = t & 63;
    const int quad = lane >> 4, c = lane & 15;
    const size_t bh = (size_t)bh_i;

    // ---- stage x[rows sc*128..+128)[h*64..+64) -> bf16 LDS, coalesced ----
    {
        const float* xg = x + ((size_t)b * S_ + sc * 128) * HID_ + h * D_;
#pragma unroll
        for (int i = 0; i < 8; ++i) {
            const int j = i * 256 + t;          // 2048 float4 segments
            const int row = j >> 4, seg = j & 15;
            float4 v = *(const float4*)(xg + (size_t)row * HID_ + seg * 4);
            short4 pk;
            pk.x = f2b(v.x); pk.y = f2b(v.y); pk.z = f2b(v.z); pk.w = f2b(v.w);
            *(short4*)&xs[row][seg * 4] = pk;
        }
    }
    __syncthreads();

    // X frags for this wave's 2 row-tiles (rows wave*32 + mt*16 + c)
    s16x8 xa[2][2];
#pragma unroll
    for (int mt = 0; mt < 2; ++mt) {
        xa[mt][0] = *(const s16x8*)&xs[wave * 32 + mt * 16 + c][quad * 8];
        xa[mt][1] = *(const s16x8*)&xs[wave * 32 + mt * 16 + c][32 + quad * 8];
    }

    const float* bs[3] = {bq, bk, bv};

#pragma unroll
    for (int m = 0; m < 3; ++m) {
        const bf16*  Wm   = Wf + ((size_t)m * H_ + h) * 4096;
        const float* bias = bs[m] + h * D_;
#pragma unroll
        for (int et = 0; et < 4; ++et) {
            s16x8 wf0 = load8bf(Wm + et * 1024 + lane * 8);         // half 0
            s16x8 wf1 = load8bf(Wm + et * 1024 + 512 + lane * 8);   // half 1
            if (m < 2) {
                // D[e][s] = W·X^T : lane holds features f = et*16+quad*4+r of
                // row s = tile*16+c. Frag target: half hp=f>>5, octet qp,
                // byte (quad&1)*4+r.
                const int hp = et >> 1;
                const int qp = (2 * et + (quad >> 1)) & 3;
                const float4 bb = *(const float4*)&bias[et * 16 + quad * 4];
                bf16* base = (m == 0 ? Qf : Kf) + bh * QK_BH;
#pragma unroll
                for (int mt = 0; mt < 2; ++mt) {
                    f32x4 acc = {0.f, 0.f, 0.f, 0.f};
                    acc = __builtin_amdgcn_mfma_f32_16x16x32_bf16(wf0, xa[mt][0], acc, 0, 0, 0);
                    acc = __builtin_amdgcn_mfma_f32_16x16x32_bf16(wf1, xa[mt][1], acc, 0, 0, 0);
                    const int ts = sc * 8 + wave * 2 + mt;   // row-tile index
                    bf16* dst = base + ts * 1024 + hp * 512 +
                                (qp * 16 + c) * 8 + (quad & 1) * 4;
                    short4 pk;
                    pk.x = f2b(acc[0] + bb.x);
                    pk.y = f2b(acc[1] + bb.y);
                    pk.z = f2b(acc[2] + bb.z);
                    pk.w = f2b(acc[3] + bb.w);
                    *(short4*)dst = pk;
                }
            } else {
                // D[s][e] = X·W^T : lane holds keys of feature et*16+c.
                const float bbv = bias[et * 16 + c];
                const int kt = sc * 2 + (wave >> 1);
                const int p  = wave & 1;
                bf16* base = Vf + bh * V_BH + kt * 4096 + et * 1024 + p * 512;
#pragma unroll
                for (int mt = 0; mt < 2; ++mt) {
                    f32x4 acc = {0.f, 0.f, 0.f, 0.f};
                    acc = __builtin_amdgcn_mfma_f32_16x16x32_bf16(xa[mt][0], wf0, acc, 0, 0, 0);
                    acc = __builtin_amdgcn_mfma_f32_16x16x32_bf16(xa[mt][1], wf1, acc, 0, 0, 0);
                    bf16* dst = base + (quad * 16 + c) * 8 + mt * 4;
                    short4 pk;
                    pk.x = f2b(acc[0] + bbv);
                    pk.y = f2b(acc[1] + bbv);
                    pk.z = f2b(acc[2] + bbv);
                    pk.w = f2b(acc[3] + bbv);
                    *(short4*)dst = pk;
                }
            }
        }
    }
}

// ---------------------------------------------------------------------------
// Kernel 2: MFMA flash attention, 32 q-rows/wave (halves the per-wave K/V
// L2 redundancy that bounds the R10 kernel: 2 GiB -> 1 GiB L2 traffic).
// Register-resident P (swap trick), fragment-order coalesced loads, softmax
// denominator computed by an extra PV MFMA against a ones-fragment (no VALU
// accumulate, no epilogue shuffles). grid 1024 (XCD swizzle bh = id&127).
// ---------------------------------------------------------------------------
__global__ __launch_bounds__(256, 3) void attn(
    const bf16* __restrict__ Qf, const bf16* __restrict__ Kf,
    const bf16* __restrict__ Vf, float* __restrict__ out)
{
    __shared__ __align__(16) float os[4][16][68];   // wave-private staging

    const int id = blockIdx.x;
    const int bh_i = id & 127, qc = id >> 7;        // qc 0..7, 128 rows each
    const int b = bh_i >> 4, h = bh_i & 15;
    const int wave = threadIdx.x >> 6, lane = threadIdx.x & 63;
    const int quad = lane >> 4, c = lane & 15;
    const int q0 = qc * 128 + wave * 32;
    const size_t bh = (size_t)bh_i;

    // Q fragments for 2 row-tiles (B-operand of swapped QK)
    s16x8 aq[2][2];
#pragma unroll
    for (int mt = 0; mt < 2; ++mt) {
        const bf16* Qb = Qf + bh * QK_BH + (qc * 8 + wave * 2 + mt) * 1024 + lane * 8;
        aq[mt][0] = load8bf(Qb);
        aq[mt][1] = load8bf(Qb + 512);
    }

    f32x4 o[2][4], ol[2];
#pragma unroll
    for (int mt = 0; mt < 2; ++mt) {
#pragma unroll
        for (int et = 0; et < 4; ++et) o[mt][et] = {0.f, 0.f, 0.f, 0.f};
        ol[mt] = {0.f, 0.f, 0.f, 0.f};
    }

    s16x8 ones;
#pragma unroll
    for (int j = 0; j < 8; ++j) ones[j] = (short)0x3F80;   // bf16 1.0

    const float CEXP = 0.18033688011112042f;           // (1/sqrt(64))*log2(e)
    const float NM0  = -16.0f * 0.18033688011112042f;  // fixed shift m0=16

    const bf16* Kb = Kf + bh * QK_BH + lane * 8;
    const bf16* Vb = Vf + bh * V_BH  + lane * 8;

#pragma unroll 1
    for (int kt = 0; kt < S_ / 64; ++kt) {
        // ---- coalesced tile loads (16 independent 16B loads) ----
        s16x8 ka[4], kb2[4];
#pragma unroll
        for (int ct = 0; ct < 4; ++ct) {
            ka[ct]  = load8bf(Kb + (kt * 4 + ct) * 1024);
            kb2[ct] = load8bf(Kb + (kt * 4 + ct) * 1024 + 512);
        }
        s16x8 vf4[4][2];
#pragma unroll
        for (int et = 0; et < 4; ++et)
#pragma unroll
            for (int p = 0; p < 2; ++p)
                vf4[et][p] = load8bf(Vb + kt * 4096 + et * 1024 + p * 512);

        // ---- S^T = K·Q^T : lane holds S[query c][key ct*16+quad*4+r] ----
        f32x4 s[2][4];
#pragma unroll
        for (int mt = 0; mt < 2; ++mt)
#pragma unroll
            for (int ct = 0; ct < 4; ++ct) {
                f32x4 acc = {0.f, 0.f, 0.f, 0.f};
                acc = __builtin_amdgcn_mfma_f32_16x16x32_bf16(ka[ct],  aq[mt][0], acc, 0, 0, 0);
                acc = __builtin_amdgcn_mfma_f32_16x16x32_bf16(kb2[ct], aq[mt][1], acc, 0, 0, 0);
                s[mt][ct] = acc;
            }

        // ---- fixed-shift softmax numerators -> A-frags; denom via MFMA ----
        s16x8 pz[2][2];
#pragma unroll
        for (int mt = 0; mt < 2; ++mt) {
#pragma unroll
            for (int p = 0; p < 2; ++p) {
                s16x8 z;
#pragma unroll
                for (int j = 0; j < 4; ++j) {
                    float pa = __builtin_amdgcn_exp2f(fmaf(s[mt][2 * p][j],     CEXP, NM0));
                    float pb = __builtin_amdgcn_exp2f(fmaf(s[mt][2 * p + 1][j], CEXP, NM0));
                    z[j]     = f2b(pa);
                    z[4 + j] = f2b(pb);
                }
                pz[mt][p] = z;
                ol[mt] = __builtin_amdgcn_mfma_f32_16x16x32_bf16(z, ones, ol[mt], 0, 0, 0);
            }
        }

        // ---- O += P·V (P never leaves registers) ----
#pragma unroll
        for (int mt = 0; mt < 2; ++mt)
#pragma unroll
            for (int et = 0; et < 4; ++et) {
                o[mt][et] = __builtin_amdgcn_mfma_f32_16x16x32_bf16(pz[mt][0], vf4[et][0], o[mt][et], 0, 0, 0);
                o[mt][et] = __builtin_amdgcn_mfma_f32_16x16x32_bf16(pz[mt][1], vf4[et][1], o[mt][et], 0, 0, 0);
            }
    }

    // ---- epilogue: inv from ol (row=query quad*4+r, replicated over c);
    //      normalize, LDS transpose, contiguous float4 stores ----
#pragma unroll
    for (int mt = 0; mt < 2; ++mt) {
        float inv[4];
#pragma unroll
        for (int r = 0; r < 4; ++r) inv[r] = 1.0f / ol[mt][r];
#pragma unroll
        for (int et = 0; et < 4; ++et)
#pragma unroll
            for (int r = 0; r < 4; ++r)
                os[wave][quad * 4 + r][et * 16 + c] = o[mt][et][r] * inv[r];
        float* orow = out + ((size_t)b * S_ + q0 + mt * 16 + c) * HID_ + h * D_;
#pragma unroll
        for (int j = 0; j < 4; ++j) {
            float4 v = *(const float4*)&os[wave][c][(quad + j * 4) * 4];
            *(float4*)(orow + (quad + j * 4) * 4) = v;
        }
    }
}

// ---------------------------------------------------------------------------
extern "C" void kernel_launch(void* const* d_in, const int* in_sizes, int n_in,
                              void* d_out, int out_size, void* d_ws, size_t ws_size,
                              hipStream_t stream) {
    (void)in_sizes; (void)n_in; (void)out_size; (void)ws_size;
    const float* x  = (const float*)d_in[0];
    const float* Wq = (const float*)d_in[1];
    const float* bq = (const float*)d_in[2];
    const float* Wk = (const float*)d_in[3];
    const float* bk = (const float*)d_in[4];
    const float* Wv = (const float*)d_in[5];
    const float* bv = (const float*)d_in[6];
    float* outp = (float*)d_out;   // reference output dtype is float32

    bf16* Qfw = (bf16*)d_ws;                       // 128 bh * 64K elems
    bf16* Kfw = Qfw + (size_t)128 * QK_BH;
    bf16* Vfw = Kfw + (size_t)128 * QK_BH;
    bf16* Wfw = Vfw + (size_t)128 * V_BH;          // + 384 KiB fragment-order W

    cvt_w<<<dim3(32, 3), 256, 0, stream>>>(Wq, Wk, Wv, Wfw);
    qkv_proj<<<dim3(1024), 256, 0, stream>>>(x, Wfw, bq, bk, bv, Qfw, Kfw, Vfw);
    attn<<<dim3(1024), 256, 0, stream>>>(Qfw, Kfw, Vfw, outp);
}

// Round 12
// 145.436 us; speedup vs baseline: 3.0874x; 1.1253x over previous
//
#include <hip/hip_runtime.h>
#include <hip/hip_bf16.h>

#define B_   8
#define S_   1024
#define HID_ 1024
#define H_   16
#define D_   64

typedef __hip_bfloat16 bf16;
typedef __attribute__((ext_vector_type(8))) short s16x8;   // MFMA A/B frag (8 bf16)
typedef __attribute__((ext_vector_type(4))) float f32x4;   // MFMA C/D frag

// Fragment-order workspace layouts (indices in bf16 elements):
//  Qf/Kf: per bh (128 KiB): 64 row-tiles of 16 rows; per tile 1024 elems =
//         [half(2)][lane(64)][8]; lane (quad,c) holds row c, features
//         half*32+quad*8..+8  (exactly the attn A/B frag).
//  Vf:    per bh: 16 key-tiles; per tile 4096 = [et(4)][p(2)][lane(64)][8];
//         lane slot = V[key p*32+quad*4+j][feat et*16+c] (j=0..3), key+16
//         for j=4..7 — the paired-chunk PV B-frag.
//  Wf:    per (m,h): 4096 = [et(4)][half(2)][lane(64)][8].
#define QK_BH 65536
#define V_BH  65536

// f32 -> bf16 bits, round-half-up (add + shift; 2 VALU)
__device__ __forceinline__ short f2b(float f) {
    union { float f; unsigned u; } a; a.f = f;
    return (short)((a.u + 0x8000u) >> 16);
}
// load 8 consecutive f32 (32B, aligned) -> bf16 half-fragment
__device__ __forceinline__ s16x8 cvt8(const float* p) {
    const float4* q = (const float4*)p;
    float4 u = q[0], v = q[1];
    s16x8 r;
    r[0] = f2b(u.x); r[1] = f2b(u.y); r[2] = f2b(u.z); r[3] = f2b(u.w);
    r[4] = f2b(v.x); r[5] = f2b(v.y); r[6] = f2b(v.z); r[7] = f2b(v.w);
    return r;
}
__device__ __forceinline__ s16x8 load8bf(const bf16* p) {
    return *(const s16x8*)p;   // 16B load; callers guarantee alignment
}

// ---------------------------------------------------------------------------
// Kernel 0: one-shot W f32 -> bf16 in FRAGMENT ORDER.
// ---------------------------------------------------------------------------
__global__ __launch_bounds__(256) void cvt_w(
    const float* __restrict__ Wq, const float* __restrict__ Wk,
    const float* __restrict__ Wv, bf16* __restrict__ Wf)
{
    const float* srcs[3] = {Wq, Wk, Wv};
    const float* src = srcs[blockIdx.y];
    bf16* dst = Wf + (size_t)blockIdx.y * (H_ * D_ * D_);
    const int i = blockIdx.x * 256 + threadIdx.x;   // 0..8191
    const int h = i >> 9;            // 512 threads per head
    const int r = i & 511;
    const int et = r >> 7, half = (r >> 6) & 1, lane = r & 63;
    const int quad = lane >> 4, c = lane & 15;
    const float* s = src + h * 4096 + (et * 16 + c) * 64 + half * 32 + quad * 8;
    bf16* d = dst + h * 4096 + et * 1024 + half * 512 + lane * 8;
    *(s16x8*)d = cvt8(s);
}

// ---------------------------------------------------------------------------
// Kernel 1: QKV projection, FRAGMENT-ORDER outputs, 64-row blocks (2x the
// parallelism of R11's 128-row version, half the per-block pipeline).
// grid 2048 (bh = id&127, sc = id>>7 over 16 chunks of 64 rows), block 256.
// Each wave owns 16 rows (one row-tile / one quarter of the V key-tile).
// ---------------------------------------------------------------------------
__global__ __launch_bounds__(256) void qkv_proj(
    const float* __restrict__ x, const bf16* __restrict__ Wf,
    const float* __restrict__ bq, const float* __restrict__ bk,
    const float* __restrict__ bv,
    bf16* __restrict__ Qf, bf16* __restrict__ Kf, bf16* __restrict__ Vf)
{
    __shared__ __align__(16) bf16 xs[64][72];   // 9 KiB, stride-72 padding

    const int id = blockIdx.x;
    const int bh_i = id & 127, sc = id >> 7;    // sc: 64-row chunk 0..15
    const int b = bh_i >> 4, h = bh_i & 15;
    const int t = threadIdx.x;
    const int wave = t >> 6, lane = t & 63;
    const int quad = lane >> 4, c = lane & 15;
    const size_t bh = (size_t)bh_i;

    // ---- stage x[rows sc*64..+64)[h*64..+64) -> bf16 LDS, coalesced ----
    {
        const float* xg = x + ((size_t)b * S_ + sc * 64) * HID_ + h * D_;
#pragma unroll
        for (int i = 0; i < 4; ++i) {
            const int j = i * 256 + t;          // 1024 float4 segments
            const int row = j >> 4, seg = j & 15;
            float4 v = *(const float4*)(xg + (size_t)row * HID_ + seg * 4);
            short4 pk;
            pk.x = f2b(v.x); pk.y = f2b(v.y); pk.z = f2b(v.z); pk.w = f2b(v.w);
            *(short4*)&xs[row][seg * 4] = pk;
        }
    }
    __syncthreads();

    // X frag for this wave's row-tile (rows wave*16 + c)
    s16x8 xa0 = *(const s16x8*)&xs[wave * 16 + c][quad * 8];
    s16x8 xa1 = *(const s16x8*)&xs[wave * 16 + c][32 + quad * 8];

    const float* bs[3] = {bq, bk, bv};

#pragma unroll
    for (int m = 0; m < 3; ++m) {
        const bf16*  Wm   = Wf + ((size_t)m * H_ + h) * 4096;
        const float* bias = bs[m] + h * D_;
#pragma unroll
        for (int et = 0; et < 4; ++et) {
            s16x8 wf0 = load8bf(Wm + et * 1024 + lane * 8);         // half 0
            s16x8 wf1 = load8bf(Wm + et * 1024 + 512 + lane * 8);   // half 1
            if (m < 2) {
                // D[e][s] = W·X^T : lane holds feats f = et*16+quad*4+r of
                // row (sc*4+wave)*16 + c.
                const int hp = et >> 1;
                const int qp = (2 * et + (quad >> 1)) & 3;
                const float4 bb = *(const float4*)&bias[et * 16 + quad * 4];
                f32x4 acc = {0.f, 0.f, 0.f, 0.f};
                acc = __builtin_amdgcn_mfma_f32_16x16x32_bf16(wf0, xa0, acc, 0, 0, 0);
                acc = __builtin_amdgcn_mfma_f32_16x16x32_bf16(wf1, xa1, acc, 0, 0, 0);
                const int ts = sc * 4 + wave;   // row-tile index
                bf16* dst = (m == 0 ? Qf : Kf) + bh * QK_BH + ts * 1024 +
                            hp * 512 + (qp * 16 + c) * 8 + (quad & 1) * 4;
                short4 pk;
                pk.x = f2b(acc[0] + bb.x);
                pk.y = f2b(acc[1] + bb.y);
                pk.z = f2b(acc[2] + bb.z);
                pk.w = f2b(acc[3] + bb.w);
                *(short4*)dst = pk;
            } else {
                // D[s][e] = X·W^T : lane holds keys wave*16+quad*4+r of
                // feature et*16+c. Key-tile = sc; p = wave>>1, hi = wave&1.
                const float bbv = bias[et * 16 + c];
                f32x4 acc = {0.f, 0.f, 0.f, 0.f};
                acc = __builtin_amdgcn_mfma_f32_16x16x32_bf16(xa0, wf0, acc, 0, 0, 0);
                acc = __builtin_amdgcn_mfma_f32_16x16x32_bf16(xa1, wf1, acc, 0, 0, 0);
                bf16* dst = Vf + bh * V_BH + sc * 4096 + et * 1024 +
                            (wave >> 1) * 512 + (quad * 16 + c) * 8 + (wave & 1) * 4;
                short4 pk;
                pk.x = f2b(acc[0] + bbv);
                pk.y = f2b(acc[1] + bbv);
                pk.z = f2b(acc[2] + bbv);
                pk.w = f2b(acc[3] + bbv);
                *(short4*)dst = pk;
            }
        }
    }
}

// ---------------------------------------------------------------------------
// Kernel 2: MFMA flash attention, 64 q-rows/wave: halves L2 K/V redundancy
// vs R11 (1 GiB -> 0.5 GiB; that term was ~29 of R11's 70 µs). Register-
// resident P (swap trick), fragment-order coalesced loads, per-lane VALU
// denominator (frees 16 VGPR + 2 MFMA/iter vs the ones-trick; the 64-VGPR
// o-accumulator needs the headroom). grid 512 (bh = id&127, qc = id>>7),
// block 256. launch_bounds(256,2): allow up to 256 VGPR — no forced spill.
// ---------------------------------------------------------------------------
__global__ __launch_bounds__(256, 2) void attn(
    const bf16* __restrict__ Qf, const bf16* __restrict__ Kf,
    const bf16* __restrict__ Vf, float* __restrict__ out)
{
    __shared__ __align__(16) float os[4][16][68];   // wave-private staging

    const int id = blockIdx.x;
    const int bh_i = id & 127, qc = id >> 7;        // qc 0..3, 256 rows each
    const int b = bh_i >> 4, h = bh_i & 15;
    const int wave = threadIdx.x >> 6, lane = threadIdx.x & 63;
    const int quad = lane >> 4, c = lane & 15;
    const int ts0 = qc * 16 + wave * 4;             // first of 4 row-tiles
    const size_t bh = (size_t)bh_i;

    // Q fragments for 4 row-tiles (B-operand of swapped QK)
    s16x8 aq[4][2];
#pragma unroll
    for (int mt = 0; mt < 4; ++mt) {
        const bf16* Qb = Qf + bh * QK_BH + (ts0 + mt) * 1024 + lane * 8;
        aq[mt][0] = load8bf(Qb);
        aq[mt][1] = load8bf(Qb + 512);
    }

    f32x4 o[4][4];
#pragma unroll
    for (int mt = 0; mt < 4; ++mt)
#pragma unroll
        for (int et = 0; et < 4; ++et) o[mt][et] = {0.f, 0.f, 0.f, 0.f};
    float l[4] = {0.f, 0.f, 0.f, 0.f};   // per-lane partial denoms

    const float CEXP = 0.18033688011112042f;           // (1/sqrt(64))*log2(e)
    const float NM0  = -16.0f * 0.18033688011112042f;  // fixed shift m0=16

    const bf16* Kb = Kf + bh * QK_BH + lane * 8;
    const bf16* Vb = Vf + bh * V_BH  + lane * 8;

#pragma unroll 1
    for (int kt = 0; kt < S_ / 64; ++kt) {
        // ---- coalesced tile loads (16 independent 16B loads) ----
        s16x8 ka[4], kb2[4];
#pragma unroll
        for (int ct = 0; ct < 4; ++ct) {
            ka[ct]  = load8bf(Kb + (kt * 4 + ct) * 1024);
            kb2[ct] = load8bf(Kb + (kt * 4 + ct) * 1024 + 512);
        }
        s16x8 vf4[4][2];
#pragma unroll
        for (int et = 0; et < 4; ++et)
#pragma unroll
            for (int p = 0; p < 2; ++p)
                vf4[et][p] = load8bf(Vb + kt * 4096 + et * 1024 + p * 512);

        // ---- per row-tile: QK^T -> softmax -> PV (P stays in registers) --
#pragma unroll
        for (int mt = 0; mt < 4; ++mt) {
            f32x4 s[4];
#pragma unroll
            for (int ct = 0; ct < 4; ++ct) {
                f32x4 acc = {0.f, 0.f, 0.f, 0.f};
                acc = __builtin_amdgcn_mfma_f32_16x16x32_bf16(ka[ct],  aq[mt][0], acc, 0, 0, 0);
                acc = __builtin_amdgcn_mfma_f32_16x16x32_bf16(kb2[ct], aq[mt][1], acc, 0, 0, 0);
                s[ct] = acc;
            }
            s16x8 pz[2];
#pragma unroll
            for (int p = 0; p < 2; ++p) {
                s16x8 z;
#pragma unroll
                for (int j = 0; j < 4; ++j) {
                    float pa = __builtin_amdgcn_exp2f(fmaf(s[2 * p][j],     CEXP, NM0));
                    float pb = __builtin_amdgcn_exp2f(fmaf(s[2 * p + 1][j], CEXP, NM0));
                    l[mt] += pa + pb;
                    z[j]     = f2b(pa);
                    z[4 + j] = f2b(pb);
                }
                pz[p] = z;
            }
#pragma unroll
            for (int et = 0; et < 4; ++et) {
                o[mt][et] = __builtin_amdgcn_mfma_f32_16x16x32_bf16(pz[0], vf4[et][0], o[mt][et], 0, 0, 0);
                o[mt][et] = __builtin_amdgcn_mfma_f32_16x16x32_bf16(pz[1], vf4[et][1], o[mt][et], 0, 0, 0);
            }
        }
    }

    // ---- epilogue per row-tile: quad-sum denom, normalize, LDS transpose,
    //      contiguous float4 stores (os reused; same-wave DS ordering) ----
#pragma unroll
    for (int mt = 0; mt < 4; ++mt) {
        float L = l[mt];
        L += __shfl_xor(L, 16, 64);
        L += __shfl_xor(L, 32, 64);
        const float Linv = 1.0f / L;
        float inv[4];
#pragma unroll
        for (int r = 0; r < 4; ++r)
            inv[r] = __shfl(Linv, quad * 4 + r, 64);
#pragma unroll
        for (int et = 0; et < 4; ++et)
#pragma unroll
            for (int r = 0; r < 4; ++r)
                os[wave][quad * 4 + r][et * 16 + c] = o[mt][et][r] * inv[r];
        float* orow = out + ((size_t)b * S_ + (ts0 + mt) * 16 + c) * HID_ + h * D_;
#pragma unroll
        for (int j = 0; j < 4; ++j) {
            float4 v = *(const float4*)&os[wave][c][(quad + j * 4) * 4];
            *(float4*)(orow + (quad + j * 4) * 4) = v;
        }
    }
}

// ---------------------------------------------------------------------------
extern "C" void kernel_launch(void* const* d_in, const int* in_sizes, int n_in,
                              void* d_out, int out_size, void* d_ws, size_t ws_size,
                              hipStream_t stream) {
    (void)in_sizes; (void)n_in; (void)out_size; (void)ws_size;
    const float* x  = (const float*)d_in[0];
    const float* Wq = (const float*)d_in[1];
    const float* bq = (const float*)d_in[2];
    const float* Wk = (const float*)d_in[3];
    const float* bk = (const float*)d_in[4];
    const float* Wv = (const float*)d_in[5];
    const float* bv = (const float*)d_in[6];
    float* outp = (float*)d_out;   // reference output dtype is float32

    bf16* Qfw = (bf16*)d_ws;                       // 128 bh * 64K elems
    bf16* Kfw = Qfw + (size_t)128 * QK_BH;
    bf16* Vfw = Kfw + (size_t)128 * QK_BH;
    bf16* Wfw = Vfw + (size_t)128 * V_BH;          // + 384 KiB fragment-order W

    cvt_w<<<dim3(32, 3), 256, 0, stream>>>(Wq, Wk, Wv, Wfw);
    qkv_proj<<<dim3(2048), 256, 0, stream>>>(x, Wfw, bq, bk, bv, Qfw, Kfw, Vfw);
    attn<<<dim3(512), 256, 0, stream>>>(Qfw, Kfw, Vfw, outp);
}